// Round 11
// baseline (326.923 us; speedup 1.0000x reference)
//
#include <hip/hip_runtime.h>

#define HWB   3136
#define HWPAD 3200
#define SPAD  3364   // 58*58 zero-padded spatial

typedef __attribute__((ext_vector_type(8))) short bf16x8;
typedef __attribute__((ext_vector_type(4))) float f32x4;

__device__ __forceinline__ unsigned short f2bf(float f) {
    unsigned u = __float_as_uint(f);
    unsigned r = (u + 0x7fffu + ((u >> 16) & 1u)) >> 16;
    return (unsigned short)r;
}
__device__ __forceinline__ float bf2f(unsigned short h) {
    return __uint_as_float(((unsigned)h) << 16);
}
__device__ __forceinline__ void gl_lds16(const void* g, void* l) {
    __builtin_amdgcn_global_load_lds(
        (const __attribute__((address_space(1))) void*)g,
        (__attribute__((address_space(3))) void*)l, 16, 0, 0);
}

// ---------------------------------------------------------------------------
// Merged prep (one dispatch, 8248 blocks):
//  [0,6272):    x f32 -> xc bf16 (same layout) + xp bf16 (padded ch-last).
//  [6272,7056): p1 -> p1t transpose.  [7056,7312): wpack.
//  [7312,8240): xp border zero.  [8240,8248): zero t5.
// ---------------------------------------------------------------------------
__global__ __launch_bounds__(256) void k_prep(
    const float* __restrict__ x, unsigned short* __restrict__ xc,
    unsigned short* __restrict__ xp,
    const float* __restrict__ p1, const float* __restrict__ cw,
    unsigned short* __restrict__ p1t, unsigned short* __restrict__ wp,
    float* __restrict__ t5)
{
    const int b = blockIdx.x, t = threadIdx.x;
    if (b < 6272) {
        __shared__ unsigned tile[64 * 33];     // dwords = channel pairs
        const int n = b / 196, rem = b - n * 196;
        const int c0 = (rem / 49) * 64, s0 = (rem % 49) * 64;
        const int cp = t >> 3;                 // 0..31 channel pair
        const int sg = (t & 7) * 8;            // s offset within tile

        const float* src = x + ((size_t)(n * 256 + c0 + 2 * cp)) * HWB + s0 + sg;
        unsigned short b0[8], b1[8];
        {
            float4 v0 = *(const float4*)(src);
            float4 v1 = *(const float4*)(src + 4);
            float4 w0 = *(const float4*)(src + HWB);
            float4 w1 = *(const float4*)(src + HWB + 4);
            b0[0] = f2bf(v0.x); b0[1] = f2bf(v0.y); b0[2] = f2bf(v0.z); b0[3] = f2bf(v0.w);
            b0[4] = f2bf(v1.x); b0[5] = f2bf(v1.y); b0[6] = f2bf(v1.z); b0[7] = f2bf(v1.w);
            b1[0] = f2bf(w0.x); b1[1] = f2bf(w0.y); b1[2] = f2bf(w0.z); b1[3] = f2bf(w0.w);
            b1[4] = f2bf(w1.x); b1[5] = f2bf(w1.y); b1[6] = f2bf(w1.z); b1[7] = f2bf(w1.w);
        }
        unsigned short* xcb = xc + ((size_t)(n * 256 + c0 + 2 * cp)) * HWB + s0 + sg;
        *(bf16x8*)xcb = *(const bf16x8*)&b0[0];
        *(bf16x8*)(xcb + HWB) = *(const bf16x8*)&b1[0];
#pragma unroll
        for (int k = 0; k < 8; ++k)
            tile[(sg + k) * 33 + cp] = (unsigned)b0[k] | ((unsigned)b1[k] << 16);
        __syncthreads();
        const int r = t >> 2;                  // 0..63 local s row
        const int cq = (t & 3) * 8;            // dword col base
        unsigned d[8];
#pragma unroll
        for (int j = 0; j < 8; ++j)
            d[j] = tile[r * 33 + cq + j];
        const int s = s0 + r;
        const int sp = s + 2 * (s / 56) + 59;  // (y+1)*58 + (x+1)
        unsigned* dst = (unsigned*)(xp + ((size_t)n * SPAD + sp) * 256 + c0 + 2 * cq);
        *(uint4*)dst = make_uint4(d[0], d[1], d[2], d[3]);
        *(uint4*)(dst + 4) = make_uint4(d[4], d[5], d[6], d[7]);
    } else if (b < 7056) {
        __shared__ unsigned short tile[32][33];
        const int b2 = b - 6272;
        const int h0 = (b2 % 98) * 32, e0 = (b2 / 98) * 32;
        const int lx = t & 31, ly = t >> 5;
#pragma unroll
        for (int it = 0; it < 4; ++it) {
            int lh = ly + it * 8;
            tile[lh][lx] = f2bf(p1[(size_t)(h0 + lh) * 256 + e0 + lx]);
        }
        __syncthreads();
#pragma unroll
        for (int it = 0; it < 4; ++it) {
            int le = ly + it * 8;
            p1t[(size_t)(e0 + le) * HWB + h0 + lx] = tile[lx][le];
        }
    } else if (b < 7312) {
        const int o = b - 7056;
#pragma unroll
        for (int k = t; k < 1152; k += 256) {
            int tap = k >> 7, ci = k & 127;
            wp[(size_t)o * 1152 + k] = f2bf(cw[(size_t)o * 1152 + ci * 9 + tap]);
        }
    } else if (b < 8240) {
        const int bb = b - 7312;
        const int n = bb / 29, xb = bb - n * 29;
        const int idx = xb * 256 + t;
        if (idx < 228 * 32) {
            const int i = idx >> 5, ch = idx & 31;
            int sp;
            if (i < 58)       sp = i;
            else if (i < 116) sp = 3306 + (i - 58);
            else if (i < 172) sp = (i - 115) * 58;
            else              sp = (i - 171) * 58 + 57;
            bf16x8 z = {};
            *(bf16x8*)&xp[((size_t)n * SPAD + sp) * 256 + ch * 8] = z;
        }
    } else {
        float4 z = {0.f, 0.f, 0.f, 0.f};
        *(float4*)&t5[(((b - 8240) * 256) + t) * 4] = z;
    }
}

// ---------------------------------------------------------------------------
// Merged MFMA dispatch (1728 blocks).  SINGLE-buffered 32KB LDS (m97-style
// 2-barrier K-step: sync -> stage -> sync/drain -> compute) -> 5 blocks/CU;
// cross-block wave overlap hides the per-block stage/drain serialization.
//  [0,128):     GEMM1 split-K=1 (K=3136, 49 steps), fused t4scale epilogue.
//  [128,1728):  grouped 3x3 conv GEMM per (n,g), K=1152, XCD-swizzled.
// ---------------------------------------------------------------------------
__global__ __launch_bounds__(256) void k_mfma(
    const unsigned short* __restrict__ xp, const unsigned short* __restrict__ wp,
    unsigned short* __restrict__ t3cl,
    const unsigned short* __restrict__ xc, const unsigned short* __restrict__ p1t,
    const float* __restrict__ p4, const float* __restrict__ p5,
    unsigned short* __restrict__ t4h, float* __restrict__ t5)
{
    __shared__ short As[128 * 64];
    __shared__ short Bs[128 * 64];
    const int tid = threadIdx.x;
    const int wave = tid >> 6, lane = tid & 63;
    const int wm = (wave >> 1) * 64, wn = (wave & 1) * 64;
    const int rl = tid >> 3, q = tid & 7;
    const int swq = (q ^ (rl & 7)) * 8;
    const int ldst = rl * 64 + q * 8;
    const int frow = lane & 15, quad = lane >> 4, sw = frow & 7;

    if (blockIdx.x >= 128) {
        // ----- conv -----
        const int orig = blockIdx.x - 128;                 // 1600 = 8 * 200
        const int wgid = (orig & 7) * 200 + (orig >> 3);
        const int ng = wgid / 25;
        const int tileS = (wgid - ng * 25) * 128;
        const int n = ng >> 1, g = ng & 1;

        const unsigned short* xpn = xp + (size_t)n * SPAD * 256 + g * 128 + swq;
        const unsigned short* arow[4];
        const unsigned short* brow[4];
#pragma unroll
        for (int p = 0; p < 4; ++p) {
            int s = tileS + p * 32 + rl;
            int sc = s < HWB ? s : HWB - 1;
            int sp = sc + 2 * (sc / 56) + 59;
            arow[p] = xpn + (size_t)sp * 256;
            brow[p] = wp + (size_t)(g * 128 + p * 32 + rl) * 1152 + swq;
        }

        f32x4 acc[4][4] = {};
        int rofA[4], rofB[4];
#pragma unroll
        for (int i = 0; i < 4; ++i) {
            rofA[i] = (wm + i * 16 + frow) * 64;
            rofB[i] = (wn + i * 16 + frow) * 64;
        }

#pragma unroll
        for (int t = 0; t < 18; ++t) {
            const int tap = t >> 1;
            const int shift = ((tap / 3 - 1) * 58 + (tap % 3 - 1)) * 256 + (t & 1) * 64;
            __syncthreads();               // previous compute done -> LDS reusable
#pragma unroll
            for (int p = 0; p < 4; ++p) {
                gl_lds16(arow[p] + shift, &As[p * 2048 + ldst]);
                gl_lds16(brow[p] + t * 64, &Bs[p * 2048 + ldst]);
            }
            __syncthreads();               // drain: staged data visible
#pragma unroll
            for (int h = 0; h < 2; ++h) {
                bf16x8 af[4], bfr[4];
#pragma unroll
                for (int i = 0; i < 4; ++i)
                    af[i] = *(const bf16x8*)&As[rofA[i] + ((h * 4 + quad) ^ sw) * 8];
#pragma unroll
                for (int j = 0; j < 4; ++j)
                    bfr[j] = *(const bf16x8*)&Bs[rofB[j] + ((h * 4 + quad) ^ sw) * 8];
#pragma unroll
                for (int i = 0; i < 4; ++i)
#pragma unroll
                    for (int j = 0; j < 4; ++j)
                        acc[i][j] = __builtin_amdgcn_mfma_f32_16x16x32_bf16(af[i], bfr[j], acc[i][j], 0, 0, 0);
            }
        }
        unsigned short* ob = t3cl + (size_t)n * HWPAD * 256 + g * 128;
#pragma unroll
        for (int i = 0; i < 4; ++i)
#pragma unroll
            for (int r = 0; r < 4; ++r) {
                int s = tileS + wm + i * 16 + quad * 4 + r;
                int c = wn + frow;
#pragma unroll
                for (int j = 0; j < 4; ++j) {
                    float v = (s < HWB) ? acc[i][j][r] : 0.f;
                    ob[(size_t)s * 256 + c + j * 16] = f2bf(v);
                }
            }
    } else {
        // ----- gemm1 (split-K=1, fused t4scale epilogue) -----
        const int orig = blockIdx.x;                      // 128 = 8 * 16
        const int wgid = (orig & 7) * 16 + (orig >> 3);
        const int tileM = (wgid >> 1) * 128;
        const int tileN = (wgid & 1) * 128;

        const unsigned short* asrc = xc + (size_t)(tileM + rl) * HWB + swq;
        const unsigned short* bsrc = p1t + (size_t)(tileN + rl) * HWB + swq;

        f32x4 acc[4][4] = {};
        for (int i2 = 0; i2 < 49; ++i2) {
            const int kn = i2 * 64;
            __syncthreads();
#pragma unroll
            for (int p = 0; p < 4; ++p) {
                gl_lds16(asrc + (size_t)(p * 32) * HWB + kn, &As[p * 2048 + ldst]);
                gl_lds16(bsrc + (size_t)(p * 32) * HWB + kn, &Bs[p * 2048 + ldst]);
            }
            __syncthreads();
#pragma unroll
            for (int h = 0; h < 2; ++h) {
                bf16x8 af[4], bfr[4];
#pragma unroll
                for (int i = 0; i < 4; ++i)
                    af[i] = *(const bf16x8*)&As[(wm + i * 16 + frow) * 64 + ((h * 4 + quad) ^ sw) * 8];
#pragma unroll
                for (int j = 0; j < 4; ++j)
                    bfr[j] = *(const bf16x8*)&Bs[(wn + j * 16 + frow) * 64 + ((h * 4 + quad) ^ sw) * 8];
#pragma unroll
                for (int i = 0; i < 4; ++i)
#pragma unroll
                    for (int j = 0; j < 4; ++j)
                        acc[i][j] = __builtin_amdgcn_mfma_f32_16x16x32_bf16(af[i], bfr[j], acc[i][j], 0, 0, 0);
            }
        }
        // fused t4scale: t4h = bf16(acc*p4); t5[m] += sum_e t4*p5 (partial)
        float p5v[4];
#pragma unroll
        for (int j = 0; j < 4; ++j)
            p5v[j] = p5[tileN + wn + j * 16 + frow];
#pragma unroll
        for (int i = 0; i < 4; ++i)
#pragma unroll
            for (int r = 0; r < 4; ++r) {
                const int m = tileM + wm + i * 16 + quad * 4 + r;
                const float* p4row = p4 + (size_t)(m & 255) * 256;
                float s = 0.f;
#pragma unroll
                for (int j = 0; j < 4; ++j) {
                    const int e = tileN + wn + j * 16 + frow;
                    const float t4v = acc[i][j][r] * p4row[e];
                    t4h[(size_t)m * 256 + e] = f2bf(t4v);
                    s += t4v * p5v[j];
                }
#pragma unroll
                for (int off = 1; off < 16; off <<= 1)
                    s += __shfl_xor(s, off);
                if (frow == 0) atomicAdd(&t5[m], s);
            }
    }
}

// ---------------------------------------------------------------------------
// BMM: out[n][a][s] = (sum_b t4h[n][a][b] * t3cl[n][s][b]) / 16 + t7[n][s]
// Single-buffered 32KB LDS (4 blocks/CU).  t7 split across all 256 threads
// (each does half a row); partials combined in epilogue via LDS.
// ---------------------------------------------------------------------------
__global__ __launch_bounds__(256) void k_bmm(
    const unsigned short* __restrict__ t4h, const unsigned short* __restrict__ t3cl,
    const unsigned short* __restrict__ xp, const float* __restrict__ t5,
    float* __restrict__ out)
{
    __shared__ short As[128 * 64];
    __shared__ short Bs[128 * 64];
    __shared__ float t5s[256];
    __shared__ float t7part[256];
    const int tid = threadIdx.x;
    const int orig = blockIdx.x;                       // 1600 = 8 * 200
    const int wgid = (orig & 7) * 200 + (orig >> 3);
    const int n = wgid / 50;
    const int rem = wgid - n * 50;
    const int tileA = (rem / 25) * 128;
    const int tileS = (rem % 25) * 128;
    const int wave = tid >> 6, lane = tid & 63;
    const int wm = (wave >> 1) * 64, wn = (wave & 1) * 64;

    const int rl = tid >> 3, q = tid & 7;
    const int swq = (q ^ (rl & 7)) * 8;
    const unsigned short* asrc = t4h + ((size_t)n * 256 + tileA + rl) * 256 + swq;
    const unsigned short* bsrc = t3cl + ((size_t)n * HWPAD + tileS + rl) * 256 + swq;

    f32x4 acc[4][4] = {};
    const int frow = lane & 15, quad = lane >> 4, sw = frow & 7;
    const int ldst = rl * 64 + q * 8;

    t5s[tid] = t5[n * 256 + tid];
    __syncthreads();                       // t5s visible to all

    // t7 partial: thread tid covers s-row (tid&127), channel half (tid>>7)
    {
        const int sLoc = tid & 127, half = tid >> 7;
        const int s = tileS + sLoc;
        float accv = 0.f;
        if (s < HWB) {
            const int sp = s + 2 * (s / 56) + 59;
            const unsigned short* row = xp + ((size_t)n * SPAD + sp) * 256 + half * 128;
            const float* wv = &t5s[half * 128];
            float p0 = 0.f, p1 = 0.f, p2 = 0.f, p3 = 0.f;
#pragma unroll
            for (int j = 0; j < 16; ++j) {
                bf16x8 v = *(const bf16x8*)(row + j * 8);
                p0 += wv[j * 8 + 0] * bf2f((unsigned short)v[0]);
                p1 += wv[j * 8 + 1] * bf2f((unsigned short)v[1]);
                p2 += wv[j * 8 + 2] * bf2f((unsigned short)v[2]);
                p3 += wv[j * 8 + 3] * bf2f((unsigned short)v[3]);
                p0 += wv[j * 8 + 4] * bf2f((unsigned short)v[4]);
                p1 += wv[j * 8 + 5] * bf2f((unsigned short)v[5]);
                p2 += wv[j * 8 + 6] * bf2f((unsigned short)v[6]);
                p3 += wv[j * 8 + 7] * bf2f((unsigned short)v[7]);
            }
            accv = (p0 + p1) + (p2 + p3);
        }
        t7part[tid] = accv;               // published by K-loop barriers
    }

#pragma unroll
    for (int k0 = 0; k0 < 256; k0 += 64) {
        __syncthreads();
#pragma unroll
        for (int p = 0; p < 4; ++p) {
            gl_lds16(asrc + (size_t)(p * 32) * 256 + k0, &As[p * 2048 + ldst]);
            gl_lds16(bsrc + (size_t)(p * 32) * 256 + k0, &Bs[p * 2048 + ldst]);
        }
        __syncthreads();
#pragma unroll
        for (int h = 0; h < 2; ++h) {
            bf16x8 af[4], bfr[4];
#pragma unroll
            for (int i = 0; i < 4; ++i)
                af[i] = *(const bf16x8*)&As[(wm + i * 16 + frow) * 64 + ((h * 4 + quad) ^ sw) * 8];
#pragma unroll
            for (int j = 0; j < 4; ++j)
                bfr[j] = *(const bf16x8*)&Bs[(wn + j * 16 + frow) * 64 + ((h * 4 + quad) ^ sw) * 8];
#pragma unroll
            for (int i = 0; i < 4; ++i)
#pragma unroll
                for (int j = 0; j < 4; ++j)
                    acc[i][j] = __builtin_amdgcn_mfma_f32_16x16x32_bf16(af[i], bfr[j], acc[i][j], 0, 0, 0);
        }
    }
    float* ob = out + (size_t)n * 256 * HWB;
#pragma unroll
    for (int j = 0; j < 4; ++j) {
        const int sLoc = wn + j * 16 + frow;
        const int s = tileS + sLoc;
        if (s >= HWB) continue;
        const float t7v = (t7part[sLoc] + t7part[sLoc + 128]) * 0.0625f;
#pragma unroll
        for (int i = 0; i < 4; ++i)
#pragma unroll
            for (int r = 0; r < 4; ++r) {
                int a = tileA + wm + i * 16 + quad * 4 + r;
                ob[(size_t)a * HWB + s] = acc[i][j][r] * 0.0625f + t7v;
            }
    }
}

extern "C" void kernel_launch(void* const* d_in, const int* in_sizes, int n_in,
                              void* d_out, int out_size, void* d_ws, size_t ws_size,
                              hipStream_t stream) {
    const float* x  = (const float*)d_in[0];
    const float* p1 = (const float*)d_in[1];
    const float* cw = (const float*)d_in[2];
    const float* p4 = (const float*)d_in[3];
    const float* p5 = (const float*)d_in[4];

    char* w = (char*)d_ws;
    unsigned short* xp    = (unsigned short*)w;  w += (size_t)32 * SPAD * 256 * 2;   // 55.1 MB
    unsigned short* t3cl  = (unsigned short*)w;  w += (size_t)32 * HWPAD * 256 * 2;  // 52.4 MB
    unsigned short* p1t   = (unsigned short*)w;  w += (size_t)256 * HWB * 2;
    unsigned short* wpack = (unsigned short*)w;  w += (size_t)256 * 1152 * 2;
    unsigned short* t4h   = (unsigned short*)w;  w += (size_t)8192 * 256 * 2;
    float* t5             = (float*)w;           w += (size_t)8192 * 4;

    // d_out doubles as scratch; xc's only consumer (k_mfma) finishes before
    // k_bmm overwrites d_out:  xc [32][256][3136] bf16 = 51.4 MB <= 102.8 MB
    char* o = (char*)d_out;
    unsigned short* xc = (unsigned short*)o;
    float* out = (float*)d_out;

    k_prep <<<dim3(8248), 256, 0, stream>>>(x, xc, xp, p1, cw, p1t, wpack, t5);
    k_mfma <<<dim3(1728), 256, 0, stream>>>(xp, wpack, t3cl, xc, p1t, p4, p5, t4h, t5);
    k_bmm  <<<dim3(1600), 256, 0, stream>>>(t4h, t3cl, xp, t5, out);
}